// Round 23
// baseline (111.590 us; speedup 1.0000x reference)
//
#include <hip/hip_runtime.h>
#include <cstdint>
#include <cstddef>

typedef unsigned long long ull;
typedef unsigned short u16;

#define N 8192
#define NWORDS 128          // 8192 / 64
#define NPOST 2000
#define NMS_THR 0.7f
#define MASKW 48            // words covered by sparse pairs (scan stops ~34)
#define SCAP 128            // cross-word bucket cap per SOURCE word (scan LDS)
#define ICAP 16             // in-word bucket cap per word (scan LDS)
#define NUNITS_P 2112       // orig-space pair units: sum_{cbq<32} 4(cbq+1)
#define RANKB 1024          // rank-role blocks (N/8)
#define UCAP 24             // pairs per unit (fixed slots)
#define SLICE_STRIDE 260    // floats; 1040B: parts hit disjoint banks

// ---------------- ws layout ----------------
// 0      : bs       float4[8192]   128 KiB (sorted clipped boxes)
// 131072 : area     f32[8192]      32 KiB  (-1.0 marks invalid box)
// 163840 : rankOf   u16[8192]      16 KiB  (orig index -> sorted rank)
// 180224 : cntU     u8[2112]       (255 = unit overflow)
// 184320 : pairBuf  u32[2112*24]   198 KiB ((a<<13)|b, a<b orig indices)

// ---------------------------------------------------------------------------
__device__ __forceinline__ float4 decode_clip_box(const float4 L, bool* valid) {
#pragma clang fp contract(off)
  float cy = L.x, cx = L.y, h = L.z, w = L.w;
  float y1 = cy - 0.5f * h;
  float x1 = cx - 0.5f * w;
  float y2 = cy + 0.5f * h;
  float x2 = cx + 0.5f * w;
  *valid = ((y2 - y1) > 16.0f) && ((x2 - x1) > 16.0f);
  float4 b;
  b.x = fminf(fmaxf(y1, 0.0f), 800.0f);
  b.y = fminf(fmaxf(x1, 0.0f), 800.0f);
  b.z = fminf(fmaxf(y2, 0.0f), 800.0f);
  b.w = fminf(fmaxf(x2, 0.0f), 800.0f);
  return b;
}

__device__ __forceinline__ float box_area(const float4 b) {
#pragma clang fp contract(off)
  return (b.z - b.x) * (b.w - b.y);   // clipped => always >= 0
}

__device__ __forceinline__ bool iou_gt_thr(const float4 a, float aa,
                                           const float4 b, float ab) {
#pragma clang fp contract(off)
  float iy = fminf(a.z, b.z) - fmaxf(a.x, b.x);
  float ix = fminf(a.w, b.w) - fmaxf(a.y, b.y);
  iy = fmaxf(iy, 0.0f);
  ix = fmaxf(ix, 0.0f);
  float inter = iy * ix;
  float uni = aa + ab - inter;
  // exact IEEE division: predicate must bit-match the numpy reference
  return (inter > 0.0f) && (uni > 0.0f) && ((inter / uni) > NMS_THR);
}

// Greedy within-word resolve from dense "who-I-suppress" (fallback only).
__device__ __forceinline__ ull resolve_word(ull dg, ull avail, int lane) {
  ull conflict = __ballot(((dg & avail) != 0ull) && ((avail >> lane) & 1ull));
  if (conflict == 0ull) return avail;
  ull dgT = 0ull;
  #pragma unroll
  for (int c = 0; c < 64; ++c) {
    ull tb = __ballot((dg >> c) & 1ull);
    if (lane == c) dgT = tb;
  }
  ull kept = avail;
  while (true) {                 // fixpoint == greedy (prefix-stabilization)
    bool sup = (dgT & kept) != 0ull;
    ull kn = avail & ~__ballot(sup);
    if (kn == kept) break;
    kept = kn;
  }
  return kept;
}

// ===========================================================================
// K1: two independent roles, one dispatch, NO cross-block dependency.
//  blocks [0, 2112): orig-space conflict pairs -> fixed per-unit slots.
//  blocks [2112, 3136): rank+gather (r22-proven) + rankOf table.
// Every output (cntU, pairBuf[<cnt], bs, area, rankOf) fully rewritten each
// call -> poison-proof, no counters to zero, no global atomics anywhere.
// ===========================================================================
__global__ __launch_bounds__(256) void rankpairs_kernel(
    const float* __restrict__ locs, const float* __restrict__ scores,
    float4* __restrict__ bs, float* __restrict__ area, u16* __restrict__ rankOf,
    unsigned char* __restrict__ cntU, unsigned* __restrict__ pairBuf) {
  __shared__ __align__(16) char smem[34336];
  int tid = threadIdx.x, bid = blockIdx.x;
  const float4* locs4 = (const float4*)locs;

  if (bid < NUNITS_P) {
    // ---------------- pairs role (orig index space) ----------------
    float4* sb = (float4*)smem;               // [4][64] boxes
    float*  sa = (float*)(smem + 4096);       // [4][64] area (-1 invalid)
    int* sCnt  = (int*)(smem + 5120);
    int* sOver = (int*)(smem + 5124);
    if (tid == 0) { *sCnt = 0; *sOver = 0; }
    int u = bid;
    int cbq = 0;                              // largest c with 2c(c+1) <= u
    while (2 * (cbq + 1) * (cbq + 2) <= u) ++cbq;
    int rb = u - 2 * cbq * (cbq + 1);         // row word
    int lane = tid & 63, cq = tid >> 6;
    int cbO = cbq * 4 + cq;                   // col word
    int j0 = cbO * 64;
    bool vC;
    float4 cbx = decode_clip_box(locs4[j0 + lane], &vC);
    sb[cq * 64 + lane] = cbx;
    sa[cq * 64 + lane] = vC ? box_area(cbx) : -1.0f;
    int i = rb * 64 + lane;
    bool vR;
    float4 r = decode_clip_box(locs4[i], &vR);
    float ai = vR ? box_area(r) : -1.0f;
    __syncthreads();
    if (cbO >= rb && ai >= 0.0f) {            // invalid i never pairs
      ull bits = 0;
      for (int c = 0; c < 64; ++c) {
        if ((j0 + c) > i && sa[cq * 64 + c] >= 0.0f &&
            iou_gt_thr(r, ai, sb[cq * 64 + c], sa[cq * 64 + c]))
          bits |= 1ull << c;
      }
      int n = (int)__popcll(bits);
      if (n) {
        int base = atomicAdd(sCnt, n);        // LDS atomic (block-local)
        int k = base;
        while (bits) {
          int c = (int)__builtin_ctzll(bits); bits &= bits - 1;
          if (k < UCAP) pairBuf[u * UCAP + k] = ((unsigned)i << 13) |
                                                (unsigned)(j0 + c);
          else *sOver = 1;
          ++k;
        }
      }
    }
    __syncthreads();
    if (tid == 0) {
      int c = *sCnt;
      cntU[u] = (unsigned char)(*sOver ? 255 : (c > UCAP ? 255 : c));
    }
    return;
  }

  // ---------------- rank role (r22-proven body) ----------------
  float* ssc = (float*)smem;                  // 33280 B staged scores
  int (*sRank)[33] = (int(*)[33])(smem + 33280);
  int brid = bid - NUNITS_P;                  // [0, 1024)
  for (int k = 0; k < 32; ++k) {
    int j = k * 256 + tid;                    // coalesced
    bool v; (void)decode_clip_box(locs4[j], &v);
    float s = v ? scores[j] : -__builtin_inff();
    ssc[(j >> 8) * SLICE_STRIDE + (j & 255)] = s;
  }
  __syncthreads();
  int boxOff = tid & 7;
  int part = tid >> 3;                        // 32 slices of 256 scores
  int i = brid * 8 + boxOff;
  float si = ssc[(i >> 8) * SLICE_STRIDE + (i & 255)];
  const float4* s4 = (const float4*)(ssc + part * SLICE_STRIDE);
  int j0 = part * 256;
  int cnt = 0;
  // j precedes i <=> s_j > s_i || (s_j == s_i && j < i)  (stable descending)
  for (int q = 0; q < 64; ++q) {
    float4 v = s4[q];                         // disjoint banksets: no conflict
    int j = j0 + 4 * q;
    cnt += (v.x > si) || ((v.x == si) & ((j + 0) < i));
    cnt += (v.y > si) || ((v.y == si) & ((j + 1) < i));
    cnt += (v.z > si) || ((v.z == si) & ((j + 2) < i));
    cnt += (v.w > si) || ((v.w == si) & ((j + 3) < i));
  }
  sRank[boxOff][part] = cnt;
  __syncthreads();
  if (tid < 8) {
    int r = 0;
    #pragma unroll
    for (int p = 0; p < 32; ++p) r += sRank[tid][p];
    int ig = brid * 8 + tid;
    bool v;
    float4 b = decode_clip_box(locs4[ig], &v);
    bs[r] = b;
    area[r] = v ? box_area(b) : -1.0f;        // sign encodes validity
    rankOf[ig] = (u16)r;
  }
}

// ===========================================================================
// K2: scan, single block.  Translates orig pairs -> rank space via rankOf,
// buckets into LDS, then runs the proven serial sparse scan (+fallback).
// ===========================================================================
__global__ __launch_bounds__(256) void scan_kernel(
    const float4* __restrict__ bs, const float* __restrict__ area,
    const u16* __restrict__ rankOf, const unsigned char* __restrict__ cntU,
    const unsigned* __restrict__ pairBuf, float* __restrict__ out) {
  __shared__ __align__(16) char smem[35840];
  int tid = threadIdx.x;

  unsigned (*sSrc)[SCAP] = (unsigned(*)[SCAP])(smem + 0);       // 24 KiB
  unsigned (*sIn)[ICAP]  = (unsigned(*)[ICAP])(smem + 24576);   // 3 KiB
  int*  sSCnt     = (int*)(smem + 27648);
  int*  sICnt     = (int*)(smem + 27840);
  ull*  sRemv     = (ull*)(smem + 28032);      // 1 KiB
  u16*  sKeptList = (u16*)(smem + 29056);      // 4000 B
  float4* sWB     = (float4*)(smem + 33056);
  float*  sWA     = (float*)(smem + 34080);
  ull*  sSupW     = (ull*)(smem + 34336);
  int*  sCtl      = (int*)(smem + 34344);      // [0]=base [1]=stop [2]=over

  if (tid < MASKW) { sSCnt[tid] = 0; sICnt[tid] = 0; }
  if (tid == 254) sCtl[0] = 0;
  if (tid == 253) sCtl[1] = 0;
  if (tid == 252) sCtl[2] = 0;
  __syncthreads();

  // sRemv from area sign, 8-deep batched loads (proven r20/r22)
  {
    int wave = tid >> 6, lane = tid & 63;
    for (int b = 0; b < 4; ++b) {
      float av[8];
      #pragma unroll
      for (int q = 0; q < 8; ++q)
        av[q] = area[(wave + (b * 8 + q) * 4) * 64 + lane];
      #pragma unroll
      for (int q = 0; q < 8; ++q) {
        ull inv = __ballot(av[q] < 0.0f);
        if (lane == 0) sRemv[wave + (b * 8 + q) * 4] = inv;
      }
    }
  }

  // translate + bucket orig pairs into LDS (order-independent sets)
  for (int u = tid; u < NUNITS_P; u += 256) {
    int c = cntU[u];
    if (c == 255) { sCtl[2] = 1; continue; }
    for (int k = 0; k < c; ++k) {
      unsigned p = pairBuf[u * UCAP + k];
      int a = (int)(p >> 13), b2 = (int)(p & 8191u);
      int ra = rankOf[a], rb2 = rankOf[b2];
      int lo = ra < rb2 ? ra : rb2;
      int hi = ra < rb2 ? rb2 : ra;
      if (hi >= MASKW * 64) continue;          // fallback region handles
      int wlo = lo >> 6, whi = hi >> 6;
      if (wlo == whi) {
        int slot = atomicAdd(&sICnt[wlo], 1);
        if (slot < ICAP)
          sIn[wlo][slot] = ((unsigned)(hi & 63) << 8) | (unsigned)(lo & 63);
        else sCtl[2] = 1;
      } else {
        int slot = atomicAdd(&sSCnt[wlo], 1);
        if (slot < SCAP)
          sSrc[wlo][slot] = ((unsigned)(lo & 63) << 13) |
                            ((unsigned)whi << 6) | (unsigned)(hi & 63);
        else sCtl[2] = 1;
      }
    }
  }
  __syncthreads();

  int sOver = sCtl[2];
  // ---- sparse masked phase (wave 0 only; proven r19..r22)
  if (!sOver && tid < 64) {
    int lane = tid;
    int base = 0;
    for (int w = 0; w < MASKW; ++w) {
      ull avail = ~sRemv[w];                   // in-order LDS: sees all ORs
      int cnI = sICnt[w];
      ull kept;
      if (cnI == 0) {
        kept = avail;
      } else {
        ull dgT = 0ull;                        // my in-word suppressors
        for (int k = 0; k < cnI; ++k) {
          unsigned p = sIn[w][k];              // uniform LDS read
          int il = (int)(p & 63u);
          int jl = (int)(p >> 8) & 63;
          if (lane == jl) dgT |= 1ull << il;
        }
        ull cf = __ballot(((dgT & avail) != 0ull) && ((avail >> lane) & 1ull));
        if (cf == 0ull) {
          kept = avail;
        } else {
          kept = avail;
          while (true) {                       // fixpoint == greedy
            bool sup = (dgT & kept) != 0ull;
            ull kn = avail & ~__ballot(sup);
            if (kn == kept) break;
            kept = kn;
          }
        }
      }
      if ((kept >> lane) & 1ull) {
        int rank = base + (int)__popcll(kept & ((1ull << lane) - 1ull));
        if (rank < NPOST) sKeptList[rank] = (u16)(w * 64 + lane);
      }
      base += (int)__popcll(kept);
      if (base >= NPOST) break;                // ranks >=2000 never emitted
      // eager push-forward: lane-parallel, no reduction
      int cnS = sSCnt[w];
      for (int k = lane; k < cnS; k += 64) {
        unsigned p = sSrc[w][k];
        int il = (int)(p >> 13) & 63;
        if ((kept >> il) & 1ull) {
          int wt = (int)(p >> 6) & 127;
          atomicOr(&sRemv[wt], 1ull << (p & 63u));   // LDS atomic
        }
      }
    }
    if (lane == 0) { sCtl[0] = base; if (base >= NPOST) sCtl[1] = 1; }
  }
  __syncthreads();

  // ---- dense fallback (correctness only; not hit by the bench input)
  int startW = sOver ? 0 : MASKW;
  if (!sCtl[1]) {
    for (int w = startW; w < NWORDS; ++w) {
      if (tid < 64) { sWB[tid] = bs[w * 64 + tid]; sWA[tid] = area[w * 64 + tid]; }
      if (tid == 0) *sSupW = sRemv[w];
      __syncthreads();
      int nk = sCtl[0];
      int c = tid & 63;
      for (int k0 = tid >> 6; k0 < nk; k0 += 4) {   // wave per kept box
        int ki = sKeptList[k0];
        float4 kb = bs[ki];                         // uniform load
        bool s = iou_gt_thr(kb, area[ki], sWB[c], sWA[c]);
        ull bits = __ballot(s);
        if (c == 0 && bits) atomicOr(sSupW, bits);
      }
      __syncthreads();
      if (tid < 64) {
        int lane = tid;
        float4 bm = sWB[lane];
        float am = sWA[lane];
        ull dg = 0;
        if (am >= 0.0f) {
          for (int cc = lane + 1; cc < 64; ++cc)
            if (sWA[cc] >= 0.0f && iou_gt_thr(bm, am, sWB[cc], sWA[cc]))
              dg |= 1ull << cc;
        }
        ull avail = ~*sSupW;
        ull kept = resolve_word(dg, avail, lane);
        int base = sCtl[0];
        if ((kept >> lane) & 1ull) {
          int rank = base + (int)__popcll(kept & ((1ull << lane) - 1ull));
          if (rank < NPOST) sKeptList[rank] = (u16)(w * 64 + lane);
        }
        if (lane == 0) {
          int nb = base + (int)__popcll(kept);
          sCtl[0] = nb;
          if (nb >= NPOST) sCtl[1] = 1;
        }
      }
      __syncthreads();
      if (sCtl[1]) break;
    }
  }

  __syncthreads();
  int total = sCtl[0];
  if (total > NPOST) total = NPOST;
  for (int r = tid; r < NPOST; r += 256) {
    float4 v = make_float4(0.0f, 0.0f, 0.0f, 0.0f);
    if (r < total) v = bs[sKeptList[r]];
    reinterpret_cast<float4*>(out)[r] = v;
  }
  // beacon: self-diagnose a repeat failure (never fires on a healthy run)
  if (total == 0 && tid == 0)
    out[0] = 5.0e9f + (float)sCtl[2] * 1.0e8f;
}

// ---------------------------------------------------------------------------
extern "C" void kernel_launch(void* const* d_in, const int* in_sizes, int n_in,
                              void* d_out, int out_size, void* d_ws, size_t ws_size,
                              hipStream_t stream) {
  const float* locs   = (const float*)d_in[0];   // (8192,4) cy,cx,h,w
  const float* scores = (const float*)d_in[1];   // (8192,)

  char* ws = (char*)d_ws;
  float4*        bs      = (float4*)(ws + 0);
  float*         area    = (float*)(ws + 131072);
  u16*           rankOf  = (u16*)(ws + 163840);
  unsigned char* cntU    = (unsigned char*)(ws + 180224);
  unsigned*      pairBuf = (unsigned*)(ws + 184320);

  rankpairs_kernel<<<NUNITS_P + RANKB, 256, 0, stream>>>(
      locs, scores, bs, area, rankOf, cntU, pairBuf);
  scan_kernel<<<1, 256, 0, stream>>>(bs, area, rankOf, cntU, pairBuf,
                                     (float*)d_out);
}

// Round 24
// 71.234 us; speedup vs baseline: 1.5665x; 1.5665x over previous
//
#include <hip/hip_runtime.h>
#include <cstdint>
#include <cstddef>

typedef unsigned long long ull;
typedef unsigned short u16;

#define N 8192
#define NWORDS 128          // 8192 / 64
#define NPOST 2000
#define NMS_THR 0.7f
#define MASKW 48            // words covered by sparse pairs (stop ~34)
#define TCAP 160            // unified pair cap per TARGET word
#define NUNITS 312          // pair units: sum_{cbq<12} 4(cbq+1) = 312
#define SLICE_STRIDE 260    // floats; 1040B: parts hit disjoint banks

// ---------------- ws layout ----------------
// 0      : bs     float4[8192]  128 KiB (sorted clipped boxes)
// 131072 : area   f32[8192]     32 KiB  (-1.0 marks invalid box)
// 163840 : ctrl   i32[64]       ([0..47] per-target-word count, [48] overflow)
// 164352 : buck   u32[48*160]   30 KiB  ((dstBit<<13)|srcRank, bucket=dst word)

// ---------------------------------------------------------------------------
__device__ __forceinline__ float4 decode_clip_box(const float4 L, bool* valid) {
#pragma clang fp contract(off)
  float cy = L.x, cx = L.y, h = L.z, w = L.w;
  float y1 = cy - 0.5f * h;
  float x1 = cx - 0.5f * w;
  float y2 = cy + 0.5f * h;
  float x2 = cx + 0.5f * w;
  *valid = ((y2 - y1) > 16.0f) && ((x2 - x1) > 16.0f);
  float4 b;
  b.x = fminf(fmaxf(y1, 0.0f), 800.0f);
  b.y = fminf(fmaxf(x1, 0.0f), 800.0f);
  b.z = fminf(fmaxf(y2, 0.0f), 800.0f);
  b.w = fminf(fmaxf(x2, 0.0f), 800.0f);
  return b;
}

__device__ __forceinline__ float box_area(const float4 b) {
#pragma clang fp contract(off)
  return (b.z - b.x) * (b.w - b.y);   // clipped => always >= 0
}

__device__ __forceinline__ bool iou_gt_thr(const float4 a, float aa,
                                           const float4 b, float ab) {
#pragma clang fp contract(off)
  float iy = fminf(a.z, b.z) - fmaxf(a.x, b.x);
  float ix = fminf(a.w, b.w) - fmaxf(a.y, b.y);
  iy = fmaxf(iy, 0.0f);
  ix = fmaxf(ix, 0.0f);
  float inter = iy * ix;
  float uni = aa + ab - inter;
  // exact IEEE division: predicate must bit-match the numpy reference
  return (inter > 0.0f) && (uni > 0.0f) && ((inter / uni) > NMS_THR);
}

// Greedy within-word resolve from dense "who-I-suppress" (fallback only).
__device__ __forceinline__ ull resolve_word(ull dg, ull avail, int lane) {
  ull conflict = __ballot(((dg & avail) != 0ull) && ((avail >> lane) & 1ull));
  if (conflict == 0ull) return avail;
  ull dgT = 0ull;
  #pragma unroll
  for (int c = 0; c < 64; ++c) {
    ull tb = __ballot((dg >> c) & 1ull);
    if (lane == c) dgT = tb;
  }
  ull kept = avail;
  while (true) {                 // fixpoint == greedy (prefix-stabilization)
    bool sup = (dgT & kept) != 0ull;
    ull kn = avail & ~__ballot(sup);
    if (kn == kept) break;
    kept = kn;
  }
  return kept;
}

// ===========================================================================
// K1: rank + gather, fused.  GRID = N/8 = 1024 blocks (proven r19..r22).
// Block 0 zeroes K2's counters (stream order -> visible to K2).
// ===========================================================================
__global__ __launch_bounds__(256) void rankgather_kernel(
    const float* __restrict__ locs, const float* __restrict__ scores,
    float4* __restrict__ bs, float* __restrict__ area, int* __restrict__ ctrl) {
  __shared__ float ssc[32 * SLICE_STRIDE];   // 33280 B, slices of 256 + pad
  __shared__ int sRank[8][33];               // +1 pad: conflict-free
  int tid = threadIdx.x, bid = blockIdx.x;
  if (bid == 0 && tid < 64) ctrl[tid] = 0;
  const float4* locs4 = (const float4*)locs;
  for (int k = 0; k < 32; ++k) {
    int j = k * 256 + tid;                   // coalesced
    bool v; (void)decode_clip_box(locs4[j], &v);
    float s = v ? scores[j] : -__builtin_inff();
    ssc[(j >> 8) * SLICE_STRIDE + (j & 255)] = s;
  }
  __syncthreads();
  int boxOff = tid & 7;
  int part = tid >> 3;                       // 32 slices of 256 scores
  int i = bid * 8 + boxOff;
  float si = ssc[(i >> 8) * SLICE_STRIDE + (i & 255)];
  const float4* s4 = (const float4*)(ssc + part * SLICE_STRIDE);
  int j0 = part * 256;
  int cnt = 0;
  // j precedes i <=> s_j > s_i || (s_j == s_i && j < i)  (stable descending)
  for (int q = 0; q < 64; ++q) {
    float4 v = s4[q];                        // 8 distinct banksets: no conflict
    int j = j0 + 4 * q;
    cnt += (v.x > si) || ((v.x == si) & ((j + 0) < i));
    cnt += (v.y > si) || ((v.y == si) & ((j + 1) < i));
    cnt += (v.z > si) || ((v.z == si) & ((j + 2) < i));
    cnt += (v.w > si) || ((v.w == si) & ((j + 3) < i));
  }
  sRank[boxOff][part] = cnt;
  __syncthreads();
  if (tid < 8) {
    int r = 0;
    #pragma unroll
    for (int p = 0; p < 32; ++p) r += sRank[tid][p];
    int ig = bid * 8 + tid;
    bool v;
    float4 b = decode_clip_box(locs4[ig], &v);
    bs[r] = b;
    area[r] = v ? box_area(b) : -1.0f;       // sign encodes validity
  }
}

// ===========================================================================
// K2: sparse conflict pairs (sorted rank space), bucketed by TARGET word.
// Entry = (dstBit<<13) | srcRank; in-word and cross-word unified.
// Plain stores/atomics — kernel boundary provides visibility.
// ===========================================================================
__global__ __launch_bounds__(256) void pairs_kernel(
    const float4* __restrict__ bs, const float* __restrict__ area,
    int* __restrict__ ctrl, unsigned* __restrict__ buck) {
  __shared__ float4 sb[4][64];
  __shared__ float  sa[4][64];
  int tid = threadIdx.x;
  int u = blockIdx.x;
  int cbq = 0;                              // largest c with 2c(c+1) <= u
  while (2 * (cbq + 1) * (cbq + 2) <= u) ++cbq;
  int rb = u - 2 * cbq * (cbq + 1);
  int lane = tid & 63, cq = tid >> 6;
  int cb = cbq * 4 + cq;                    // target word, < MASKW
  int j0 = cb * 64;
  sb[cq][lane] = bs[j0 + lane];
  sa[cq][lane] = area[j0 + lane];
  int i = rb * 64 + lane;
  float4 r = bs[i];
  float ai = area[i];
  __syncthreads();
  if (cb < rb || ai < 0.0f) return;         // invalid i never pairs
  ull bits = 0;
  for (int c = 0; c < 64; ++c) {
    if ((j0 + c) > i && sa[cq][c] >= 0.0f &&
        iou_gt_thr(r, ai, sb[cq][c], sa[cq][c]))
      bits |= 1ull << c;
  }
  int n = (int)__popcll(bits);
  if (!n) return;
  int base = atomicAdd(&ctrl[cb], n);
  if (base + n > TCAP) { ctrl[48] = 1; return; }
  int k = base;
  while (bits) {
    int c = (int)__builtin_ctzll(bits); bits &= bits - 1;
    buck[cb * TCAP + k++] = ((unsigned)c << 13) | (unsigned)i;
  }
}

// ===========================================================================
// K3: scan via parallel Jacobi fixpoint (lane w owns word w).
// kept = valid & ~(exists kept suppressor) iterated to convergence == greedy
// (induction on rank-dependency depth; <=3072 iters guaranteed, ~5 typical).
// Replaces the ~24us 48-step serial word chain with ~5 cheap iterations.
// ===========================================================================
__global__ __launch_bounds__(256) void scan_kernel(
    const float4* __restrict__ bs, const float* __restrict__ area,
    const int* __restrict__ ctrl, const unsigned* __restrict__ buck,
    float* __restrict__ out) {
  __shared__ __align__(16) char smem[37760];
  int tid = threadIdx.x;

  unsigned (*sBuck)[TCAP] = (unsigned(*)[TCAP])(smem + 0);   // 30720 B
  int*  sCnt      = (int*)(smem + 30720);      // 192 B
  ull*  sRemv     = (ull*)(smem + 30912);      // 1 KiB (invalid bits)
  ull*  sKept     = (ull*)(smem + 31936);      // 512 B
  u16*  sKeptList = (u16*)(smem + 32448);      // 4000 B
  float4* sWB     = (float4*)(smem + 36448);
  float*  sWA     = (float*)(smem + 37472);
  ull*  sSupW     = (ull*)(smem + 37728);
  int*  sCtl      = (int*)(smem + 37736);      // [0]=total [1]=stop [2]=over

  // sRemv (invalid bitmap) from area sign, 8-deep batched loads (proven r20)
  {
    int wave = tid >> 6, lane = tid & 63;
    for (int b = 0; b < 4; ++b) {
      float av[8];
      #pragma unroll
      for (int q = 0; q < 8; ++q)
        av[q] = area[(wave + (b * 8 + q) * 4) * 64 + lane];
      #pragma unroll
      for (int q = 0; q < 8; ++q) {
        ull inv = __ballot(av[q] < 0.0f);
        if (lane == 0) sRemv[wave + (b * 8 + q) * 4] = inv;
      }
    }
  }
  if (tid == 254) sCtl[0] = 0;
  if (tid == 253) sCtl[1] = 0;
  if (tid < MASKW) sCnt[tid] = ctrl[tid];
  if (tid == 255) sCtl[2] = ctrl[48];
  {
    const uint4* b4 = (const uint4*)buck;              // 1920 uint4
    uint4* d4 = (uint4*)sBuck;
    #pragma unroll
    for (int k = 0; k < 8; ++k) {
      int idx = tid + k * 256;
      if (idx < (MASKW * TCAP) / 4) d4[idx] = b4[idx];
    }
  }
  __syncthreads();

  int sOver = sCtl[2];
  // ---- Jacobi fixpoint + emit (wave 0; lane w owns word w) ----
  if (!sOver && tid < 64) {
    int w = tid;
    ull validw = (w < MASKW) ? ~sRemv[w] : 0ull;
    int cw = (w < MASKW) ? sCnt[w] : 0;
    if (cw > TCAP) cw = TCAP;
    ull kept = validw;
    for (int it = 0; it < 3072; ++it) {      // converges ~5 iters typical
      sKept[w] = kept;                        // same-wave DS order: visible
      ull sup = 0;
      for (int k = 0; k < cw; ++k) {
        unsigned e = sBuck[w][k];
        int sr = (int)(e & 8191u);            // suppressor rank (< dst rank)
        if ((sKept[sr >> 6] >> (sr & 63)) & 1ull) sup |= 1ull << (e >> 13);
      }
      ull kn = validw & ~sup;
      ull chg = __ballot(kn != kept);
      kept = kn;
      if (chg == 0ull) break;
    }
    sKept[w] = kept;
    // prefix-scan of counts across lanes (one-time shfl scan)
    int cnt_w = (int)__popcll(kept);
    int inc = cnt_w;
    #pragma unroll
    for (int d = 1; d < 64; d <<= 1) {
      int t = __shfl_up(inc, d, 64);
      if (w >= d) inc += t;
    }
    int idx = inc - cnt_w;                   // exclusive prefix
    ull kb = kept;
    while (kb) {
      int b = (int)__builtin_ctzll(kb); kb &= kb - 1;
      if (idx < NPOST) sKeptList[idx] = (u16)(w * 64 + b);
      ++idx;
    }
    if (w == 63) {                           // lanes 48-63 contribute 0
      sCtl[0] = inc;
      if (inc >= NPOST) sCtl[1] = 1;
    }
  }
  __syncthreads();

  // ---- dense fallback (overflow: from word 0; short: from word 48) ----
  int startW = sOver ? 0 : MASKW;
  if (!sCtl[1]) {
    for (int w = startW; w < NWORDS; ++w) {
      if (tid < 64) { sWB[tid] = bs[w * 64 + tid]; sWA[tid] = area[w * 64 + tid]; }
      if (tid == 0) *sSupW = sRemv[w];
      __syncthreads();
      int nk = sCtl[0];
      int c = tid & 63;
      for (int k0 = tid >> 6; k0 < nk; k0 += 4) {   // wave per kept box
        int ki = sKeptList[k0];
        float4 kb = bs[ki];                         // uniform load
        bool s = iou_gt_thr(kb, area[ki], sWB[c], sWA[c]);
        ull bits = __ballot(s);
        if (c == 0 && bits) atomicOr(sSupW, bits);
      }
      __syncthreads();
      if (tid < 64) {
        int lane = tid;
        float4 bm = sWB[lane];
        float am = sWA[lane];
        ull dg = 0;
        if (am >= 0.0f) {
          for (int cc = lane + 1; cc < 64; ++cc)
            if (sWA[cc] >= 0.0f && iou_gt_thr(bm, am, sWB[cc], sWA[cc]))
              dg |= 1ull << cc;
        }
        ull avail = ~*sSupW;
        ull kept = resolve_word(dg, avail, lane);
        int base = sCtl[0];
        if ((kept >> lane) & 1ull) {
          int rank = base + (int)__popcll(kept & ((1ull << lane) - 1ull));
          if (rank < NPOST) sKeptList[rank] = (u16)(w * 64 + lane);
        }
        if (lane == 0) {
          int nb = base + (int)__popcll(kept);
          sCtl[0] = nb;
          if (nb >= NPOST) sCtl[1] = 1;
        }
      }
      __syncthreads();
      if (sCtl[1]) break;
    }
  }

  __syncthreads();
  int total = sCtl[0];
  if (total > NPOST) total = NPOST;
  for (int r = tid; r < NPOST; r += 256) {
    float4 v = make_float4(0.0f, 0.0f, 0.0f, 0.0f);
    if (r < total) v = bs[sKeptList[r]];
    reinterpret_cast<float4*>(out)[r] = v;
  }
  // beacon: self-diagnose a repeat failure (never fires on a healthy run)
  if (total == 0 && tid == 0)
    out[0] = 5.0e9f + (float)sCtl[2] * 1.0e8f;
}

// ---------------------------------------------------------------------------
extern "C" void kernel_launch(void* const* d_in, const int* in_sizes, int n_in,
                              void* d_out, int out_size, void* d_ws, size_t ws_size,
                              hipStream_t stream) {
  const float* locs   = (const float*)d_in[0];   // (8192,4) cy,cx,h,w
  const float* scores = (const float*)d_in[1];   // (8192,)

  char* ws = (char*)d_ws;
  float4*   bs   = (float4*)(ws + 0);
  float*    area = (float*)(ws + 131072);
  int*      ctrl = (int*)(ws + 163840);
  unsigned* buck = (unsigned*)(ws + 164352);

  rankgather_kernel<<<N / 8, 256, 0, stream>>>(locs, scores, bs, area, ctrl);
  pairs_kernel<<<NUNITS, 256, 0, stream>>>(bs, area, ctrl, buck);
  scan_kernel<<<1, 256, 0, stream>>>(bs, area, ctrl, buck, (float*)d_out);
}

// Round 25
// 60.998 us; speedup vs baseline: 1.8294x; 1.1678x over previous
//
#include <hip/hip_runtime.h>
#include <cstdint>
#include <cstddef>

typedef unsigned long long ull;
typedef unsigned short u16;

#define N 8192
#define NWORDS 128          // 8192 / 64
#define NPOST 2000
#define NMS_THR 0.7f
#define MASKW 48            // words covered by sparse pairs (scan stops ~34)
#define SCAP 128            // cross-word pair cap per SOURCE word
#define ICAP 16             // in-word pair cap per word
#define NUNITS 312          // pair units: sum_{cbq<12} 4(cbq+1) = 312
#define SLICE_STRIDE 260    // floats; 1040B: parts hit disjoint banks

// ---------------- ws layout ----------------
// 0      : bs       float4[8192]  128 KiB (sorted clipped boxes)
// 131072 : area     f32[8192]     32 KiB  (-1.0 marks invalid box)
// 163840 : ctrl     i32[64]       ([0..47] srcCnt, [48] overflow)
// 164096 : inCnt    i32[64]
// 164352 : srcBuf   u32[48*128]   24 KiB  ((il<<13)|(wt<<6)|jl, bucket=src word)
// 188928 : inBuf    u32[48*16]    3 KiB   ((jl<<8)|il per in-word pair)

// ---------------------------------------------------------------------------
__device__ __forceinline__ float4 decode_clip_box(const float4 L, bool* valid) {
#pragma clang fp contract(off)
  float cy = L.x, cx = L.y, h = L.z, w = L.w;
  float y1 = cy - 0.5f * h;
  float x1 = cx - 0.5f * w;
  float y2 = cy + 0.5f * h;
  float x2 = cx + 0.5f * w;
  *valid = ((y2 - y1) > 16.0f) && ((x2 - x1) > 16.0f);
  float4 b;
  b.x = fminf(fmaxf(y1, 0.0f), 800.0f);
  b.y = fminf(fmaxf(x1, 0.0f), 800.0f);
  b.z = fminf(fmaxf(y2, 0.0f), 800.0f);
  b.w = fminf(fmaxf(x2, 0.0f), 800.0f);
  return b;
}

__device__ __forceinline__ float box_area(const float4 b) {
#pragma clang fp contract(off)
  return (b.z - b.x) * (b.w - b.y);   // clipped => always >= 0
}

__device__ __forceinline__ bool iou_gt_thr(const float4 a, float aa,
                                           const float4 b, float ab) {
#pragma clang fp contract(off)
  float iy = fminf(a.z, b.z) - fmaxf(a.x, b.x);
  float ix = fminf(a.w, b.w) - fmaxf(a.y, b.y);
  iy = fmaxf(iy, 0.0f);
  ix = fmaxf(ix, 0.0f);
  float inter = iy * ix;
  float uni = aa + ab - inter;
  // exact IEEE division: predicate must bit-match the numpy reference
  return (inter > 0.0f) && (uni > 0.0f) && ((inter / uni) > NMS_THR);
}

// Greedy within-word resolve from dense "who-I-suppress" (fallback only).
__device__ __forceinline__ ull resolve_word(ull dg, ull avail, int lane) {
  ull conflict = __ballot(((dg & avail) != 0ull) && ((avail >> lane) & 1ull));
  if (conflict == 0ull) return avail;
  ull dgT = 0ull;
  #pragma unroll
  for (int c = 0; c < 64; ++c) {
    ull tb = __ballot((dg >> c) & 1ull);
    if (lane == c) dgT = tb;
  }
  ull kept = avail;
  while (true) {                 // fixpoint == greedy (prefix-stabilization)
    bool sup = (dgT & kept) != 0ull;
    ull kn = avail & ~__ballot(sup);
    if (kn == kept) break;
    kept = kn;
  }
  return kept;
}

// ===========================================================================
// K1: rank + gather, fused.  GRID = N/8 = 1024 blocks (proven r19..r22).
// Block 0 zeroes K2's counters (stream order -> visible to K2).
// ===========================================================================
__global__ __launch_bounds__(256) void rankgather_kernel(
    const float* __restrict__ locs, const float* __restrict__ scores,
    float4* __restrict__ bs, float* __restrict__ area,
    int* __restrict__ ctrl, int* __restrict__ inCnt) {
  __shared__ float ssc[32 * SLICE_STRIDE];   // 33280 B, slices of 256 + pad
  __shared__ int sRank[8][33];               // +1 pad: conflict-free
  int tid = threadIdx.x, bid = blockIdx.x;
  if (bid == 0) {
    if (tid < 64) ctrl[tid] = 0;
    else if (tid < 128) inCnt[tid - 64] = 0;
  }
  const float4* locs4 = (const float4*)locs;
  for (int k = 0; k < 32; ++k) {
    int j = k * 256 + tid;                   // coalesced
    bool v; (void)decode_clip_box(locs4[j], &v);
    float s = v ? scores[j] : -__builtin_inff();
    ssc[(j >> 8) * SLICE_STRIDE + (j & 255)] = s;
  }
  __syncthreads();
  int boxOff = tid & 7;
  int part = tid >> 3;                       // 32 slices of 256 scores
  int i = bid * 8 + boxOff;
  float si = ssc[(i >> 8) * SLICE_STRIDE + (i & 255)];
  const float4* s4 = (const float4*)(ssc + part * SLICE_STRIDE);
  int j0 = part * 256;
  int cnt = 0;
  // j precedes i <=> s_j > s_i || (s_j == s_i && j < i)  (stable descending)
  for (int q = 0; q < 64; ++q) {
    float4 v = s4[q];                        // 8 distinct banksets: no conflict
    int j = j0 + 4 * q;
    cnt += (v.x > si) || ((v.x == si) & ((j + 0) < i));
    cnt += (v.y > si) || ((v.y == si) & ((j + 1) < i));
    cnt += (v.z > si) || ((v.z == si) & ((j + 2) < i));
    cnt += (v.w > si) || ((v.w == si) & ((j + 3) < i));
  }
  sRank[boxOff][part] = cnt;
  __syncthreads();
  if (tid < 8) {
    int r = 0;
    #pragma unroll
    for (int p = 0; p < 32; ++p) r += sRank[tid][p];
    int ig = bid * 8 + tid;
    bool v;
    float4 b = decode_clip_box(locs4[ig], &v);
    bs[r] = b;
    area[r] = v ? box_area(b) : -1.0f;       // sign encodes validity
  }
}

// ===========================================================================
// K2: sparse conflict pairs, standalone (r9/r22-proven).  One unit per
// block; PLAIN stores/atomics — the kernel boundary provides visibility.
// ===========================================================================
__global__ __launch_bounds__(256) void pairs_kernel(
    const float4* __restrict__ bs, const float* __restrict__ area,
    int* __restrict__ ctrl, int* __restrict__ inCnt,
    unsigned* __restrict__ srcBuf, unsigned* __restrict__ inBuf) {
  __shared__ float4 sb[4][64];
  __shared__ float  sa[4][64];
  int tid = threadIdx.x;
  int u = blockIdx.x;
  int cbq = 0;                              // largest c with 2c(c+1) <= u
  while (2 * (cbq + 1) * (cbq + 2) <= u) ++cbq;
  int rb = u - 2 * cbq * (cbq + 1);
  int lane = tid & 63, cq = tid >> 6;
  int cb = cbq * 4 + cq;
  int j0 = cb * 64;
  sb[cq][lane] = bs[j0 + lane];
  sa[cq][lane] = area[j0 + lane];
  int i = rb * 64 + lane;
  float4 r = bs[i];
  float ai = area[i];
  __syncthreads();
  if (cb < rb || ai < 0.0f) return;         // invalid i never pairs
  ull bits = 0;
  for (int c = 0; c < 64; ++c) {
    if ((j0 + c) > i && sa[cq][c] >= 0.0f &&
        iou_gt_thr(r, ai, sb[cq][c], sa[cq][c]))
      bits |= 1ull << c;
  }
  int n = (int)__popcll(bits);
  if (!n) return;
  if (cb == rb) {                           // in-word pairs (bucket = word)
    int base = atomicAdd(&inCnt[cb], n);
    if (base + n > ICAP) { ctrl[48] = 1; return; }
    int k = base;
    while (bits) {
      int c = (int)__builtin_ctzll(bits); bits &= bits - 1;
      inBuf[cb * ICAP + k++] = ((unsigned)c << 8) | (unsigned)lane;
    }
  } else {                                  // cross pairs, bucket = SOURCE rb
    int base = atomicAdd(&ctrl[rb], n);
    if (base + n > SCAP) { ctrl[48] = 1; return; }
    int k = base;
    while (bits) {
      int c = (int)__builtin_ctzll(bits); bits &= bits - 1;
      srcBuf[rb * SCAP + k++] =             // (il<<13) | (wt<<6) | jl
          ((unsigned)lane << 13) | ((unsigned)cb << 6) | (unsigned)c;
    }
  }
}

// ===========================================================================
// K3: greedy scan, standalone single block (r22-proven: serial word walk
// with eager lane-parallel push-forward; plain loads — kernel boundary
// gives fresh data).
// ===========================================================================
__global__ __launch_bounds__(256) void scan_kernel(
    const float4* __restrict__ bs, const float* __restrict__ area,
    const int* __restrict__ ctrl, const int* __restrict__ inCnt,
    const unsigned* __restrict__ srcBuf, const unsigned* __restrict__ inBuf,
    float* __restrict__ out) {
  __shared__ __align__(16) char smem[35840];
  int tid = threadIdx.x;

  unsigned (*sSrc)[SCAP] = (unsigned(*)[SCAP])(smem + 0);       // 24 KiB
  unsigned (*sIn)[ICAP]  = (unsigned(*)[ICAP])(smem + 24576);   // 3 KiB
  int*  sSCnt     = (int*)(smem + 27648);
  int*  sICnt     = (int*)(smem + 27840);
  ull*  sRemv     = (ull*)(smem + 28032);      // 1 KiB
  u16*  sKeptList = (u16*)(smem + 29056);      // 4000 B
  float4* sWB     = (float4*)(smem + 33056);
  float*  sWA     = (float*)(smem + 34080);
  ull*  sSupW     = (ull*)(smem + 34336);
  int*  sCtl      = (int*)(smem + 34344);      // [0]=base [1]=stop [2]=over

  // sRemv from area sign, 8-deep batched loads (proven r20/r22)
  {
    int wave = tid >> 6, lane = tid & 63;
    for (int b = 0; b < 4; ++b) {
      float av[8];
      #pragma unroll
      for (int q = 0; q < 8; ++q)
        av[q] = area[(wave + (b * 8 + q) * 4) * 64 + lane];
      #pragma unroll
      for (int q = 0; q < 8; ++q) {
        ull inv = __ballot(av[q] < 0.0f);
        if (lane == 0) sRemv[wave + (b * 8 + q) * 4] = inv;
      }
    }
  }
  if (tid == 254) sCtl[0] = 0;
  if (tid == 253) sCtl[1] = 0;
  if (tid < MASKW) { sSCnt[tid] = ctrl[tid]; sICnt[tid] = inCnt[tid]; }
  if (tid == 255) sCtl[2] = ctrl[48];
  {
    const uint4* src4 = (const uint4*)srcBuf;          // 1536 uint4
    uint4* dst4 = (uint4*)sSrc;
    #pragma unroll
    for (int k = 0; k < 6; ++k) dst4[tid + k * 256] = src4[tid + k * 256];
    const uint4* in4 = (const uint4*)inBuf;            // 192 uint4
    if (tid < 192) ((uint4*)sIn)[tid] = in4[tid];
  }
  __syncthreads();

  int sOver = sCtl[2];
  // ---- sparse masked phase (wave 0 only; no shfl/reduce in the loop)
  if (!sOver && tid < 64) {
    int lane = tid;
    int base = 0;
    for (int w = 0; w < MASKW; ++w) {
      ull avail = ~sRemv[w];                   // in-order LDS: sees all ORs
      int cnI = sICnt[w];
      ull kept;
      if (cnI == 0) {
        kept = avail;
      } else {
        ull dgT = 0ull;                        // my in-word suppressors
        for (int k = 0; k < cnI; ++k) {
          unsigned p = sIn[w][k];              // uniform LDS read
          int il = (int)(p & 63u);
          int jl = (int)(p >> 8) & 63;
          if (lane == jl) dgT |= 1ull << il;
        }
        ull cf = __ballot(((dgT & avail) != 0ull) && ((avail >> lane) & 1ull));
        if (cf == 0ull) {
          kept = avail;
        } else {
          kept = avail;
          while (true) {                       // fixpoint == greedy
            bool sup = (dgT & kept) != 0ull;
            ull kn = avail & ~__ballot(sup);
            if (kn == kept) break;
            kept = kn;
          }
        }
      }
      if ((kept >> lane) & 1ull) {
        int rank = base + (int)__popcll(kept & ((1ull << lane) - 1ull));
        if (rank < NPOST) sKeptList[rank] = (u16)(w * 64 + lane);
      }
      base += (int)__popcll(kept);
      if (base >= NPOST) break;                // ranks >=2000 never emitted
      // eager push-forward: lane-parallel, no reduction
      int cnS = sSCnt[w];
      for (int k = lane; k < cnS; k += 64) {
        unsigned p = sSrc[w][k];
        int il = (int)(p >> 13) & 63;
        if ((kept >> il) & 1ull) {
          int wt = (int)(p >> 6) & 127;
          atomicOr(&sRemv[wt], 1ull << (p & 63u));   // LDS atomic
        }
      }
    }
    if (lane == 0) { sCtl[0] = base; if (base >= NPOST) sCtl[1] = 1; }
  }
  __syncthreads();

  // ---- dense fallback (correctness only; not hit by the bench input)
  int startW = sOver ? 0 : MASKW;
  if (!sCtl[1]) {
    for (int w = startW; w < NWORDS; ++w) {
      if (tid < 64) { sWB[tid] = bs[w * 64 + tid]; sWA[tid] = area[w * 64 + tid]; }
      if (tid == 0) *sSupW = sRemv[w];
      __syncthreads();
      int nk = sCtl[0];
      int c = tid & 63;
      for (int k0 = tid >> 6; k0 < nk; k0 += 4) {   // wave per kept box
        int ki = sKeptList[k0];
        float4 kb = bs[ki];                         // uniform load
        bool s = iou_gt_thr(kb, area[ki], sWB[c], sWA[c]);
        ull bits = __ballot(s);
        if (c == 0 && bits) atomicOr(sSupW, bits);
      }
      __syncthreads();
      if (tid < 64) {
        int lane = tid;
        float4 bm = sWB[lane];
        float am = sWA[lane];
        ull dg = 0;
        if (am >= 0.0f) {
          for (int cc = lane + 1; cc < 64; ++cc)
            if (sWA[cc] >= 0.0f && iou_gt_thr(bm, am, sWB[cc], sWA[cc]))
              dg |= 1ull << cc;
        }
        ull avail = ~*sSupW;
        ull kept = resolve_word(dg, avail, lane);
        int base = sCtl[0];
        if ((kept >> lane) & 1ull) {
          int rank = base + (int)__popcll(kept & ((1ull << lane) - 1ull));
          if (rank < NPOST) sKeptList[rank] = (u16)(w * 64 + lane);
        }
        if (lane == 0) {
          int nb = base + (int)__popcll(kept);
          sCtl[0] = nb;
          if (nb >= NPOST) sCtl[1] = 1;
        }
      }
      __syncthreads();
      if (sCtl[1]) break;
    }
  }

  __syncthreads();
  int total = sCtl[0];
  if (total > NPOST) total = NPOST;
  for (int r = tid; r < NPOST; r += 256) {
    float4 v = make_float4(0.0f, 0.0f, 0.0f, 0.0f);
    if (r < total) v = bs[sKeptList[r]];
    reinterpret_cast<float4*>(out)[r] = v;
  }
  // beacon: self-diagnose a repeat failure (never fires on a healthy run)
  if (total == 0 && tid == 0)
    out[0] = 5.0e9f + (float)sCtl[2] * 1.0e8f;
}

// ---------------------------------------------------------------------------
extern "C" void kernel_launch(void* const* d_in, const int* in_sizes, int n_in,
                              void* d_out, int out_size, void* d_ws, size_t ws_size,
                              hipStream_t stream) {
  const float* locs   = (const float*)d_in[0];   // (8192,4) cy,cx,h,w
  const float* scores = (const float*)d_in[1];   // (8192,)

  char* ws = (char*)d_ws;
  float4*   bs       = (float4*)(ws + 0);
  float*    area     = (float*)(ws + 131072);
  int*      ctrl     = (int*)(ws + 163840);
  int*      inCnt    = (int*)(ws + 164096);
  unsigned* srcBuf   = (unsigned*)(ws + 164352);
  unsigned* inBuf    = (unsigned*)(ws + 188928);

  rankgather_kernel<<<N / 8, 256, 0, stream>>>(locs, scores, bs, area, ctrl, inCnt);
  pairs_kernel<<<NUNITS, 256, 0, stream>>>(bs, area, ctrl, inCnt, srcBuf, inBuf);
  scan_kernel<<<1, 256, 0, stream>>>(bs, area, ctrl, inCnt, srcBuf, inBuf,
                                     (float*)d_out);
}